// Round 5
// baseline (350.073 us; speedup 1.0000x reference)
//
#include <hip/hip_runtime.h>
#include <hip/hip_bf16.h>
#include <stdint.h>

typedef __hip_bfloat16 bf16;
typedef __attribute__((ext_vector_type(4))) float f32x4;
typedef __attribute__((ext_vector_type(8))) short s16x8;
typedef __attribute__((ext_vector_type(4))) short s16x4;

#define DEV static __device__ __forceinline__

DEV short f2bf(float f) {
  bf16 h = __float2bfloat16(f);
  short s;
  __builtin_memcpy(&s, &h, 2);
  return s;
}
DEV float bf2f(short s) {
  bf16 h;
  __builtin_memcpy(&h, &s, 2);
  return __bfloat162float(h);
}

// ------------- transpose + f32->bf16 convert: W[K][N] -> Wt[N][K] ----------
__global__ __launch_bounds__(256) void transpose_cvt(
    const float* __restrict__ W, bf16* __restrict__ Wt, int K, int N)
{
  __shared__ float tile[32][33];
  const int n0 = blockIdx.x << 5;
  const int k0 = blockIdx.y << 5;
  const int tx = threadIdx.x & 31, ty = threadIdx.x >> 5;
#pragma unroll
  for (int i = 0; i < 4; ++i)
    tile[ty + i * 8][tx] = W[(size_t)(k0 + ty + i * 8) * N + n0 + tx];
  __syncthreads();
#pragma unroll
  for (int i = 0; i < 4; ++i)
    Wt[(size_t)(n0 + ty + i * 8) * K + k0 + tx] = __float2bfloat16(tile[tx][ty + i * 8]);
}

// ------------- layernorm (f32 in, bf16 out), D = 1024 ---------------------
__global__ __launch_bounds__(256) void ln_bf16(
    const float* __restrict__ x, const float* __restrict__ g,
    const float* __restrict__ be, bf16* __restrict__ out)
{
  const int t = threadIdx.x;
  const size_t row = blockIdx.x;
  const float4 v = ((const float4*)(x + row * 1024))[t];
  float s = v.x + v.y + v.z + v.w;
  float ss = v.x * v.x + v.y * v.y + v.z * v.z + v.w * v.w;
#pragma unroll
  for (int off = 32; off > 0; off >>= 1) {
    s += __shfl_down(s, off);
    ss += __shfl_down(ss, off);
  }
  __shared__ float sh[8];
  const int wave = t >> 6, lane = t & 63;
  if (!lane) { sh[wave] = s; sh[4 + wave] = ss; }
  __syncthreads();
  s = sh[0] + sh[1] + sh[2] + sh[3];
  ss = sh[4] + sh[5] + sh[6] + sh[7];
  const float mean = s * (1.f / 1024.f);
  const float rstd = rsqrtf(ss * (1.f / 1024.f) - mean * mean + 1e-5f);
  const float4 gv = ((const float4*)g)[t];
  const float4 bv = ((const float4*)be)[t];
  s16x4 o;
  o[0] = f2bf((v.x - mean) * rstd * gv.x + bv.x);
  o[1] = f2bf((v.y - mean) * rstd * gv.y + bv.y);
  o[2] = f2bf((v.z - mean) * rstd * gv.z + bv.z);
  o[3] = f2bf((v.w - mean) * rstd * gv.w + bv.w);
  ((s16x4*)(out + row * 1024))[t] = o;
}

// ------------- residual add + layernorm ------------------------------------
__global__ __launch_bounds__(256) void add_ln_bf16(
    const float* __restrict__ a, const float* __restrict__ x,
    const float* __restrict__ g, const float* __restrict__ be,
    bf16* __restrict__ xres, bf16* __restrict__ xnorm)
{
  const int t = threadIdx.x;
  const size_t row = blockIdx.x;
  const float4 av = ((const float4*)(a + row * 1024))[t];
  const float4 xv = ((const float4*)(x + row * 1024))[t];
  float4 v;
  v.x = av.x + xv.x; v.y = av.y + xv.y; v.z = av.z + xv.z; v.w = av.w + xv.w;
  float s = v.x + v.y + v.z + v.w;
  float ss = v.x * v.x + v.y * v.y + v.z * v.z + v.w * v.w;
#pragma unroll
  for (int off = 32; off > 0; off >>= 1) {
    s += __shfl_down(s, off);
    ss += __shfl_down(ss, off);
  }
  __shared__ float sh[8];
  const int wave = t >> 6, lane = t & 63;
  if (!lane) { sh[wave] = s; sh[4 + wave] = ss; }
  __syncthreads();
  s = sh[0] + sh[1] + sh[2] + sh[3];
  ss = sh[4] + sh[5] + sh[6] + sh[7];
  const float mean = s * (1.f / 1024.f);
  const float rstd = rsqrtf(ss * (1.f / 1024.f) - mean * mean + 1e-5f);
  const float4 gv = ((const float4*)g)[t];
  const float4 bv = ((const float4*)be)[t];
  s16x4 r, o;
  r[0] = f2bf(v.x); r[1] = f2bf(v.y); r[2] = f2bf(v.z); r[3] = f2bf(v.w);
  o[0] = f2bf((v.x - mean) * rstd * gv.x + bv.x);
  o[1] = f2bf((v.y - mean) * rstd * gv.y + bv.y);
  o[2] = f2bf((v.z - mean) * rstd * gv.z + bv.z);
  o[3] = f2bf((v.w - mean) * rstd * gv.w + bv.w);
  ((s16x4*)(xres + row * 1024))[t] = r;
  ((s16x4*)(xnorm + row * 1024))[t] = o;
}

// ------------- GEMM: C[M][N] = A[M][K] @ Bt[N][K]^T, bf16 MFMA -------------
// 2-phase pipelined 128x128 tile, BK=32, double-buffered LDS, counted-drain
// AFTER compute (T3-minimum), raw s_barrier (1/iter), bijective XCD swizzle.
// EPI 0: C bf16 plain. EPI 1: bf16 relu(C + bias). EPI 2: f32 C + bias + add.
template <int EPI>
__global__ __launch_bounds__(256) void gemm_bt(
    const bf16* __restrict__ A, const bf16* __restrict__ Bt,
    void* __restrict__ C, const float* __restrict__ bias,
    const bf16* __restrict__ add_bf16, int M, int N, int K)
{
  __shared__ bf16 sA[2][128 * 32];
  __shared__ bf16 sB[2][128 * 32];
  const int tid = threadIdx.x;
  const int wave = tid >> 6, lane = tid & 63;
  const int fr = lane & 15, fg = lane >> 4;
  const int wr = wave >> 1, wc = wave & 1;
  const int nbx = N >> 7;
  // bijective XCD-aware swizzle (all our grids are %8==0; fall back otherwise)
  int bid = blockIdx.x;
  if ((gridDim.x & 7) == 0) {
    const int cpx = gridDim.x >> 3;
    bid = (bid & 7) * cpx + (bid >> 3);
  }
  const int brow = (bid / nbx) << 7;
  const int bcol = (bid % nbx) << 7;

  f32x4 acc[4][4] = {};

  const int c0 = wave * 64 + lane;   // staging chunk (16B) index, round 0
  const int c1 = c0 + 256;           // round 1
  const size_t ga0 = (size_t)(brow + (c0 >> 2)) * K + (c0 & 3) * 8;
  const size_t ga1 = (size_t)(brow + (c1 >> 2)) * K + (c1 & 3) * 8;
  const size_t gb0 = (size_t)(bcol + (c0 >> 2)) * K + (c0 & 3) * 8;
  const size_t gb1 = (size_t)(bcol + (c1 >> 2)) * K + (c1 & 3) * 8;
  const int la0 = (wave * 64) * 8;          // LDS element offsets within a buffer
  const int la1 = la0 + 256 * 8;

#define GSTAGE(bi, kt)                                                         \
  do {                                                                         \
    __builtin_amdgcn_global_load_lds(                                          \
        (const __attribute__((address_space(1))) uint32_t*)(A + ga0 + (kt)),   \
        (__attribute__((address_space(3))) uint32_t*)(&sA[bi][la0]), 16, 0, 0);\
    __builtin_amdgcn_global_load_lds(                                          \
        (const __attribute__((address_space(1))) uint32_t*)(A + ga1 + (kt)),   \
        (__attribute__((address_space(3))) uint32_t*)(&sA[bi][la1]), 16, 0, 0);\
    __builtin_amdgcn_global_load_lds(                                          \
        (const __attribute__((address_space(1))) uint32_t*)(Bt + gb0 + (kt)),  \
        (__attribute__((address_space(3))) uint32_t*)(&sB[bi][la0]), 16, 0, 0);\
    __builtin_amdgcn_global_load_lds(                                          \
        (const __attribute__((address_space(1))) uint32_t*)(Bt + gb1 + (kt)),  \
        (__attribute__((address_space(3))) uint32_t*)(&sB[bi][la1]), 16, 0, 0);\
  } while (0)

  GSTAGE(0, 0);
  asm volatile("s_waitcnt vmcnt(0)" ::: "memory");
  __builtin_amdgcn_s_barrier();
  __builtin_amdgcn_sched_barrier(0);

  int cur = 0;
  for (int kt = 0; kt < K; kt += 32) {
    const bool more = (kt + 32 < K);
    if (more) GSTAGE(cur ^ 1, kt + 32);   // issue next tile BEFORE compute

    s16x8 af[4], bfr[4];
#pragma unroll
    for (int m = 0; m < 4; ++m)
      af[m] = *(const s16x8*)(&sA[cur][(wr * 64 + m * 16 + fr) * 32 + fg * 8]);
#pragma unroll
    for (int n = 0; n < 4; ++n)
      bfr[n] = *(const s16x8*)(&sB[cur][(wc * 64 + n * 16 + fr) * 32 + fg * 8]);
#pragma unroll
    for (int m = 0; m < 4; ++m)
#pragma unroll
      for (int n = 0; n < 4; ++n)
        acc[m][n] = __builtin_amdgcn_mfma_f32_16x16x32_bf16(af[m], bfr[n], acc[m][n], 0, 0, 0);

    if (more) {
      asm volatile("s_waitcnt vmcnt(0)" ::: "memory");  // next tile landed
      __builtin_amdgcn_s_barrier();                     // all waves done reading cur
      __builtin_amdgcn_sched_barrier(0);
    }
    cur ^= 1;
  }
#undef GSTAGE

  const int crow = brow + wr * 64;
  const int ccol = bcol + wc * 64;
#pragma unroll
  for (int m = 0; m < 4; ++m) {
#pragma unroll
    for (int n = 0; n < 4; ++n) {
      const int col = ccol + n * 16 + fr;
#pragma unroll
      for (int j = 0; j < 4; ++j) {
        const int row = crow + m * 16 + fg * 4 + j;
        float v = acc[m][n][j];
        if (EPI == 0) {
          ((bf16*)C)[(size_t)row * N + col] = __float2bfloat16(v);
        } else if (EPI == 1) {
          v += bias[col];
          v = fmaxf(v, 0.f);
          ((bf16*)C)[(size_t)row * N + col] = __float2bfloat16(v);
        } else {
          float a;
          {
            bf16 hb = add_bf16[(size_t)row * N + col];
            a = __bfloat162float(hb);
          }
          ((float*)C)[(size_t)row * N + col] = v + bias[col] + a;
        }
      }
    }
  }
}

// ------------- flash attention v4 ------------------------------------------
// QK [4096][2048] bf16 (Q cols 0..1023, K cols 1024..2047), Vt [1024][4096] bf16
// (row = h*64+d, col = b*2048+s).  Out [4096][1024] f32.
// grid (16 q-tiles of 128, 32 bh), 512 threads = 8 waves, each wave owns 16
// q-rows, ALL waves share the k-range. Per 64-k tile, K (64x64) and V (64x64)
// are staged once into LDS via global_load_lds (1 K-chunk + 1 V-chunk per
// wave), XOR-swizzled via pre-swizzled GLOBAL source (rule: linear LDS dest +
// inverse-swz source + swz read). 2-phase pipeline: stage(t+1) issued before
// compute(t); counted vmcnt + raw s_barrier (no full drain).
__global__ __launch_bounds__(512, 4) void attn_fwd(
    const bf16* __restrict__ QK, const bf16* __restrict__ Vt,
    float* __restrict__ Out)
{
  const int LDK = 2048;
  const int qt = blockIdx.x;
  const int bh = blockIdx.y;
  const int b = bh >> 4, h = bh & 15;
  const int tid = threadIdx.x;
  const int wave = tid >> 6, lane = tid & 63;
  const int fr = lane & 15, fg = lane >> 4;
  const int f7 = fr & 7;

  const short* base = (const short*)QK + (size_t)b * 2048 * LDK;
  const short* Qp = base + h * 64;
  const short* Kp = base + 1024 + h * 64;
  const short* Vp = (const short*)Vt + (size_t)h * 64 * 4096 + b * 2048;
  const int q0 = qt * 128 + wave * 16;

  // LDS: K tile [64 k][64 d] and V tile [64 d][64 k], both row=128B,
  // 16B-chunk index XOR-swizzled by (row&7). Double buffered.
  __shared__ short Kbuf[2][64 * 64];
  __shared__ short Vbuf[2][64 * 64];
  __shared__ short P_lds[8][16 * 72];
  short* Pw = P_lds[wave];

  // staging source addresses (per lane): chunk s = wave, row = 8s + (l>>3),
  // logical 16B-chunk = (l&7) ^ (l>>3)   [inverse of the read-side swizzle]
  const int rsub = lane >> 3;              // 0..7
  const int clog = (lane & 7) ^ rsub;      // source chunk (shorts: *8)
  const short* Ksrc = Kp + (size_t)(8 * wave + rsub) * LDK + clog * 8;
  const short* Vsrc = Vp + (size_t)(8 * wave + rsub) * 4096 + clog * 8;

  // Q fragment, pre-scaled by 1/sqrt(64) = 0.125 (exact in bf16)
  s16x8 qf0 = *(const s16x8*)(Qp + (size_t)(q0 + fr) * LDK + fg * 8);
  s16x8 qf1 = *(const s16x8*)(Qp + (size_t)(q0 + fr) * LDK + 32 + fg * 8);
#pragma unroll
  for (int i = 0; i < 8; ++i) {
    qf0[i] = f2bf(bf2f(qf0[i]) * 0.125f);
    qf1[i] = f2bf(bf2f(qf1[i]) * 0.125f);
  }

  f32x4 acc[4] = {};
  f32x4 mrow = {-1e30f, -1e30f, -1e30f, -1e30f};
  f32x4 lrow = {};   // per-lane partial; fr-reduced once at the end

#define STAGE(bi, kt)                                                          \
  do {                                                                         \
    __builtin_amdgcn_global_load_lds(                                          \
        (const __attribute__((address_space(1))) uint32_t*)(Ksrc + (size_t)(kt) * LDK), \
        (__attribute__((address_space(3))) uint32_t*)(&Kbuf[bi][wave * 512]),  \
        16, 0, 0);                                                             \
    __builtin_amdgcn_global_load_lds(                                          \
        (const __attribute__((address_space(1))) uint32_t*)(Vsrc + (kt)),      \
        (__attribute__((address_space(3))) uint32_t*)(&Vbuf[bi][wave * 512]),  \
        16, 0, 0);                                                             \
  } while (0)

  int cur = 0;
  STAGE(0, 0);

  for (int kt = 0; kt < 2048; kt += 64) {
    // ---- phase A: prefetch next tile, then wait for current tile ----
    if (kt + 64 < 2048) {
      STAGE(cur ^ 1, kt + 64);
      asm volatile("s_waitcnt vmcnt(2)" ::: "memory");
    } else {
      asm volatile("s_waitcnt vmcnt(0)" ::: "memory");
    }
    __builtin_amdgcn_s_barrier();          // all waves' chunks landed
    __builtin_amdgcn_sched_barrier(0);

    const short* Kb = Kbuf[cur];
    const short* Vb = Vbuf[cur];

    // ---- QK^T: e[t] = 16x16 tile (q rows x k cols), swizzled LDS reads ----
    f32x4 e[4];
#pragma unroll
    for (int t = 0; t < 4; ++t) {
      const int ro = (t * 16 + fr) * 64;
      const s16x8 k0 = *(const s16x8*)(Kb + ro + ((fg ^ f7) << 3));
      const s16x8 k1 = *(const s16x8*)(Kb + ro + (((4 + fg) ^ f7) << 3));
      f32x4 z = {};
      z = __builtin_amdgcn_mfma_f32_16x16x32_bf16(qf0, k0, z, 0, 0, 0);
      z = __builtin_amdgcn_mfma_f32_16x16x32_bf16(qf1, k1, z, 0, 0, 0);
      e[t] = z;
    }

    // ---- per-lane defer-max: cross-lane tree + rescale only on growth > 8 ----
    f32x4 lmx;
#pragma unroll
    for (int j = 0; j < 4; ++j)
      lmx[j] = fmaxf(fmaxf(e[0][j], e[1][j]), fmaxf(e[2][j], e[3][j]));
    const bool need = (lmx[0] > mrow[0] + 8.f) | (lmx[1] > mrow[1] + 8.f) |
                      (lmx[2] > mrow[2] + 8.f) | (lmx[3] > mrow[3] + 8.f);
    if (__any(need)) {
      f32x4 mx = lmx;
#pragma unroll
      for (int d = 1; d < 16; d <<= 1)
#pragma unroll
        for (int j = 0; j < 4; ++j) mx[j] = fmaxf(mx[j], __shfl_xor(mx[j], d));
#pragma unroll
      for (int j = 0; j < 4; ++j) {
        const float mn = fmaxf(mrow[j], mx[j]);
        const float al = __expf(mrow[j] - mn);
        lrow[j] *= al;
        mrow[j] = mn;
#pragma unroll
        for (int nn = 0; nn < 4; ++nn) acc[nn][j] *= al;
      }
    }

    // ---- exp in place + per-lane partial row-sum ----
#pragma unroll
    for (int j = 0; j < 4; ++j) {
#pragma unroll
      for (int t = 0; t < 4; ++t) e[t][j] = __expf(e[t][j] - mrow[j]);
      lrow[j] += (e[0][j] + e[1][j]) + (e[2][j] + e[3][j]);
    }

    // ---- P transpose through wave-private LDS (in-order DS, no barrier) ----
#pragma unroll
    for (int t = 0; t < 4; ++t)
#pragma unroll
      for (int j = 0; j < 4; ++j)
        Pw[(fg * 4 + j) * 72 + t * 16 + fr] = f2bf(e[t][j]);
    const s16x8 pf0 = *(const s16x8*)(Pw + fr * 72 + fg * 8);
    const s16x8 pf1 = *(const s16x8*)(Pw + fr * 72 + 32 + fg * 8);

    // ---- PV from swizzled V tile ----
#pragma unroll
    for (int nn = 0; nn < 4; ++nn) {
      const int ro = (nn * 16 + fr) * 64;
      const s16x8 vf0 = *(const s16x8*)(Vb + ro + ((fg ^ f7) << 3));
      const s16x8 vf1 = *(const s16x8*)(Vb + ro + (((4 + fg) ^ f7) << 3));
      acc[nn] = __builtin_amdgcn_mfma_f32_16x16x32_bf16(pf0, vf0, acc[nn], 0, 0, 0);
      acc[nn] = __builtin_amdgcn_mfma_f32_16x16x32_bf16(pf1, vf1, acc[nn], 0, 0, 0);
    }

    // ---- end barrier: everyone done reading buf[cur]; next iter's STAGE
    //      may overwrite it only after this point ----
    __builtin_amdgcn_s_barrier();
    __builtin_amdgcn_sched_barrier(0);
    cur ^= 1;
  }
#undef STAGE

  // ---- final fr-reduction of lrow, normalize + store ----
#pragma unroll
  for (int d = 1; d < 16; d <<= 1)
#pragma unroll
    for (int j = 0; j < 4; ++j) lrow[j] += __shfl_xor(lrow[j], d);
  f32x4 inv;
#pragma unroll
  for (int j = 0; j < 4; ++j) inv[j] = 1.0f / lrow[j];
  float* outp = Out + (size_t)(b * 2048 + q0) * 1024 + h * 64;
#pragma unroll
  for (int nn = 0; nn < 4; ++nn)
#pragma unroll
    for (int j = 0; j < 4; ++j)
      outp[(size_t)(fg * 4 + j) * 1024 + nn * 16 + fr] = acc[nn][j] * inv[j];
}

// ---------------------------------------------------------------------------
extern "C" void kernel_launch(void* const* d_in, const int* in_sizes, int n_in,
                              void* d_out, int out_size, void* d_ws, size_t ws_size,
                              hipStream_t stream)
{
  const float* x   = (const float*)d_in[0];
  const float* Wq  = (const float*)d_in[1];
  const float* Wk  = (const float*)d_in[2];
  const float* Wv  = (const float*)d_in[3];
  const float* W1  = (const float*)d_in[4];
  const float* b1  = (const float*)d_in[5];
  const float* W2  = (const float*)d_in[6];
  const float* b2  = (const float*)d_in[7];
  const float* g1  = (const float*)d_in[8];
  const float* be1 = (const float*)d_in[9];
  const float* g2  = (const float*)d_in[10];
  const float* be2 = (const float*)d_in[11];
  float* out = (float*)d_out;

  const int M = 4096, D = 1024, DF = 4096;

  // workspace layout (lifetime-overlapped), total ~86 MB
  bf16* Wqk_t = (bf16*)d_ws;                        // [2048][1024]
  bf16* Wv_t  = Wqk_t + (size_t)2048 * 1024;        // [1024][1024]
  bf16* W1t   = Wv_t + (size_t)1024 * 1024;         // [4096][1024]
  bf16* W2t   = W1t + (size_t)4096 * 1024;          // [1024][4096]
  bf16* big   = W2t + (size_t)4096 * 1024;          // 16M elems = 32MB
  bf16* QK    = big;                                // [4096][2048] (dead after attn)
  bf16* Vt    = big + (size_t)8 * 1024 * 1024;      // [1024][4096] (dead after attn)
  bf16* hbuf  = big;                                // [4096][4096] (FFN1 out)
  char* p2    = (char*)(big + (size_t)16 * 1024 * 1024);
  bf16* xnorm = (bf16*)p2;                          // [4096][1024] (dead after gemms)
  float* attnO = (float*)p2;                        // [4096][1024] f32 (reuses xnorm)
  char* p3    = p2 + (size_t)M * D * sizeof(float);
  bf16* xres  = (bf16*)p3;                          // [4096][1024]
  bf16* xnorm2 = xres + (size_t)M * D;              // [4096][1024]

  // 1. weight transpose+convert
  transpose_cvt<<<dim3(32, 32), 256, 0, stream>>>(Wq, Wqk_t, D, D);
  transpose_cvt<<<dim3(32, 32), 256, 0, stream>>>(Wk, Wqk_t + (size_t)D * D, D, D);
  transpose_cvt<<<dim3(32, 32), 256, 0, stream>>>(Wv, Wv_t, D, D);
  transpose_cvt<<<dim3(128, 32), 256, 0, stream>>>(W1, W1t, D, DF);
  transpose_cvt<<<dim3(32, 128), 256, 0, stream>>>(W2, W2t, DF, D);
  // 2. LN1
  ln_bf16<<<M, 256, 0, stream>>>(x, g1, be1, xnorm);
  // 3. QK projection (fused Wq|Wk), row-major [4096][2048]
  gemm_bt<0><<<(M / 128) * (2048 / 128), 256, 0, stream>>>(
      xnorm, Wqk_t, QK, nullptr, nullptr, M, 2048, D);
  // 4. V projection directly transposed: Vt[d][s] = sum_k Wv_t[d][k]*xnorm[s][k]
  gemm_bt<0><<<(D / 128) * (M / 128), 256, 0, stream>>>(
      Wv_t, xnorm, Vt, nullptr, nullptr, D, M, D);
  // 5. attention (8 waves sharing LDS-staged K/V tiles, 2-phase pipeline)
  attn_fwd<<<dim3(16, 32), 512, 0, stream>>>(QK, Vt, attnO);
  // 6. residual + LN2
  add_ln_bf16<<<M, 256, 0, stream>>>(attnO, x, g2, be2, xres, xnorm2);
  // 7. FFN1 (bias + relu fused)
  gemm_bt<1><<<(M / 128) * (DF / 128), 256, 0, stream>>>(
      xres, W1t, hbuf, b1, nullptr, M, DF, D);
  // 8. FFN2 (bias + x_norm2 add fused) -> f32 out
  gemm_bt<2><<<(M / 128) * (D / 128), 256, 0, stream>>>(
      hbuf, W2t, out, b2, xnorm2, M, D, DF);
}

// Round 6
// 273.221 us; speedup vs baseline: 1.2813x; 1.2813x over previous
//
#include <hip/hip_runtime.h>
#include <hip/hip_bf16.h>
#include <stdint.h>

typedef __hip_bfloat16 bf16;
typedef __attribute__((ext_vector_type(4))) float f32x4;
typedef __attribute__((ext_vector_type(8))) short s16x8;
typedef __attribute__((ext_vector_type(4))) short s16x4;

#define DEV static __device__ __forceinline__

DEV short f2bf(float f) {
  bf16 h = __float2bfloat16(f);
  short s;
  __builtin_memcpy(&s, &h, 2);
  return s;
}
DEV float bf2f(short s) {
  bf16 h;
  __builtin_memcpy(&h, &s, 2);
  return __bfloat162float(h);
}

// ------------- transpose + f32->bf16 convert: W[K][N] -> Wt[N][K] ----------
__global__ __launch_bounds__(256) void transpose_cvt(
    const float* __restrict__ W, bf16* __restrict__ Wt, int K, int N)
{
  __shared__ float tile[32][33];
  const int n0 = blockIdx.x << 5;
  const int k0 = blockIdx.y << 5;
  const int tx = threadIdx.x & 31, ty = threadIdx.x >> 5;
#pragma unroll
  for (int i = 0; i < 4; ++i)
    tile[ty + i * 8][tx] = W[(size_t)(k0 + ty + i * 8) * N + n0 + tx];
  __syncthreads();
#pragma unroll
  for (int i = 0; i < 4; ++i)
    Wt[(size_t)(n0 + ty + i * 8) * K + k0 + tx] = __float2bfloat16(tile[tx][ty + i * 8]);
}

// ------------- layernorm (f32 in, bf16 out), D = 1024 ---------------------
__global__ __launch_bounds__(256) void ln_bf16(
    const float* __restrict__ x, const float* __restrict__ g,
    const float* __restrict__ be, bf16* __restrict__ out)
{
  const int t = threadIdx.x;
  const size_t row = blockIdx.x;
  const float4 v = ((const float4*)(x + row * 1024))[t];
  float s = v.x + v.y + v.z + v.w;
  float ss = v.x * v.x + v.y * v.y + v.z * v.z + v.w * v.w;
#pragma unroll
  for (int off = 32; off > 0; off >>= 1) {
    s += __shfl_down(s, off);
    ss += __shfl_down(ss, off);
  }
  __shared__ float sh[8];
  const int wave = t >> 6, lane = t & 63;
  if (!lane) { sh[wave] = s; sh[4 + wave] = ss; }
  __syncthreads();
  s = sh[0] + sh[1] + sh[2] + sh[3];
  ss = sh[4] + sh[5] + sh[6] + sh[7];
  const float mean = s * (1.f / 1024.f);
  const float rstd = rsqrtf(ss * (1.f / 1024.f) - mean * mean + 1e-5f);
  const float4 gv = ((const float4*)g)[t];
  const float4 bv = ((const float4*)be)[t];
  s16x4 o;
  o[0] = f2bf((v.x - mean) * rstd * gv.x + bv.x);
  o[1] = f2bf((v.y - mean) * rstd * gv.y + bv.y);
  o[2] = f2bf((v.z - mean) * rstd * gv.z + bv.z);
  o[3] = f2bf((v.w - mean) * rstd * gv.w + bv.w);
  ((s16x4*)(out + row * 1024))[t] = o;
}

// ------------- residual add + layernorm ------------------------------------
__global__ __launch_bounds__(256) void add_ln_bf16(
    const float* __restrict__ a, const float* __restrict__ x,
    const float* __restrict__ g, const float* __restrict__ be,
    bf16* __restrict__ xres, bf16* __restrict__ xnorm)
{
  const int t = threadIdx.x;
  const size_t row = blockIdx.x;
  const float4 av = ((const float4*)(a + row * 1024))[t];
  const float4 xv = ((const float4*)(x + row * 1024))[t];
  float4 v;
  v.x = av.x + xv.x; v.y = av.y + xv.y; v.z = av.z + xv.z; v.w = av.w + xv.w;
  float s = v.x + v.y + v.z + v.w;
  float ss = v.x * v.x + v.y * v.y + v.z * v.z + v.w * v.w;
#pragma unroll
  for (int off = 32; off > 0; off >>= 1) {
    s += __shfl_down(s, off);
    ss += __shfl_down(ss, off);
  }
  __shared__ float sh[8];
  const int wave = t >> 6, lane = t & 63;
  if (!lane) { sh[wave] = s; sh[4 + wave] = ss; }
  __syncthreads();
  s = sh[0] + sh[1] + sh[2] + sh[3];
  ss = sh[4] + sh[5] + sh[6] + sh[7];
  const float mean = s * (1.f / 1024.f);
  const float rstd = rsqrtf(ss * (1.f / 1024.f) - mean * mean + 1e-5f);
  const float4 gv = ((const float4*)g)[t];
  const float4 bv = ((const float4*)be)[t];
  s16x4 r, o;
  r[0] = f2bf(v.x); r[1] = f2bf(v.y); r[2] = f2bf(v.z); r[3] = f2bf(v.w);
  o[0] = f2bf((v.x - mean) * rstd * gv.x + bv.x);
  o[1] = f2bf((v.y - mean) * rstd * gv.y + bv.y);
  o[2] = f2bf((v.z - mean) * rstd * gv.z + bv.z);
  o[3] = f2bf((v.w - mean) * rstd * gv.w + bv.w);
  ((s16x4*)(xres + row * 1024))[t] = r;
  ((s16x4*)(xnorm + row * 1024))[t] = o;
}

// ------------- GEMM: C[M][N] = A[M][K] @ Bt[N][K]^T, bf16 MFMA -------------
// 128x128 tile, BK=64, single LDS buffer, __syncthreads structure (R4-proven),
// XCD-bijective block swizzle, T2 XOR-swizzled LDS (chunk ^= row&7) applied
// both-sides: linear global_load_lds dest + pre-swizzled global source +
// swizzled ds_read -> conflict-free b128 fragment reads.
// EPI 0: C bf16 plain. EPI 1: bf16 relu(C + bias). EPI 2: f32 C + bias + add.
template <int EPI>
__global__ __launch_bounds__(256) void gemm_bt(
    const bf16* __restrict__ A, const bf16* __restrict__ Bt,
    void* __restrict__ C, const float* __restrict__ bias,
    const bf16* __restrict__ add_bf16, int M, int N, int K)
{
  __shared__ bf16 sA[128 * 64];
  __shared__ bf16 sB[128 * 64];
  const int tid = threadIdx.x;
  const int wave = tid >> 6, lane = tid & 63;
  const int fr = lane & 15, fg = lane >> 4;
  const int f7 = fr & 7;
  const int wr = wave >> 1, wc = wave & 1;
  const int nbx = N >> 7;
  // bijective XCD-aware swizzle (all our grids are %8==0; fall back otherwise)
  int bid = blockIdx.x;
  if ((gridDim.x & 7) == 0) {
    const int cpx = gridDim.x >> 3;
    bid = (bid & 7) * cpx + (bid >> 3);
  }
  const int brow = (bid / nbx) << 7;
  const int bcol = (bid % nbx) << 7;

  f32x4 acc[4][4] = {};

  // staging: each wave stages 32 rows (4 loads x 8 rows) of A and of B.
  // lane -> row_sub = lane>>3, phys chunk = lane&7, logical chunk = phys ^ row_sub
  const int rsub = lane >> 3;              // 0..7
  const int cl = (lane & 7) ^ rsub;        // logical 16B chunk in source row
  size_t ga[4], gb[4];
  int la[4];
#pragma unroll
  for (int j = 0; j < 4; ++j) {
    const int r = wave * 32 + j * 8;       // first row of this load
    ga[j] = (size_t)(brow + r + rsub) * K + cl * 8;
    gb[j] = (size_t)(bcol + r + rsub) * K + cl * 8;
    la[j] = r * 64;                        // wave-uniform LDS base (elements)
  }

  for (int kt = 0; kt < K; kt += 64) {
#pragma unroll
    for (int j = 0; j < 4; ++j) {
      __builtin_amdgcn_global_load_lds(
          (const __attribute__((address_space(1))) uint32_t*)(A + ga[j] + kt),
          (__attribute__((address_space(3))) uint32_t*)(&sA[la[j]]), 16, 0, 0);
      __builtin_amdgcn_global_load_lds(
          (const __attribute__((address_space(1))) uint32_t*)(Bt + gb[j] + kt),
          (__attribute__((address_space(3))) uint32_t*)(&sB[la[j]]), 16, 0, 0);
    }
    __syncthreads();

    // fragment reads: row*64 + ((kk*4+fg)^(row&7))*8 ; row&7 == fr&7
    s16x8 af[4][2], bfr[4][2];
#pragma unroll
    for (int m = 0; m < 4; ++m)
#pragma unroll
      for (int kk = 0; kk < 2; ++kk)
        af[m][kk] = *(const s16x8*)(&sA[(wr * 64 + m * 16 + fr) * 64 +
                                        (((kk * 4 + fg) ^ f7) << 3)]);
#pragma unroll
    for (int n = 0; n < 4; ++n)
#pragma unroll
      for (int kk = 0; kk < 2; ++kk)
        bfr[n][kk] = *(const s16x8*)(&sB[(wc * 64 + n * 16 + fr) * 64 +
                                         (((kk * 4 + fg) ^ f7) << 3)]);
#pragma unroll
    for (int kk = 0; kk < 2; ++kk)
#pragma unroll
      for (int m = 0; m < 4; ++m)
#pragma unroll
        for (int n = 0; n < 4; ++n)
          acc[m][n] = __builtin_amdgcn_mfma_f32_16x16x32_bf16(
              af[m][kk], bfr[n][kk], acc[m][n], 0, 0, 0);
    __syncthreads();
  }

  const int crow = brow + wr * 64;
  const int ccol = bcol + wc * 64;
#pragma unroll
  for (int m = 0; m < 4; ++m) {
#pragma unroll
    for (int n = 0; n < 4; ++n) {
      const int col = ccol + n * 16 + fr;
#pragma unroll
      for (int j = 0; j < 4; ++j) {
        const int row = crow + m * 16 + fg * 4 + j;
        float v = acc[m][n][j];
        if (EPI == 0) {
          ((bf16*)C)[(size_t)row * N + col] = __float2bfloat16(v);
        } else if (EPI == 1) {
          v += bias[col];
          v = fmaxf(v, 0.f);
          ((bf16*)C)[(size_t)row * N + col] = __float2bfloat16(v);
        } else {
          float a;
          {
            bf16 hb = add_bf16[(size_t)row * N + col];
            a = __bfloat162float(hb);
          }
          ((float*)C)[(size_t)row * N + col] = v + bias[col] + a;
        }
      }
    }
  }
}

// ------------- flash attention v4 ------------------------------------------
// QK [4096][2048] bf16 (Q cols 0..1023, K cols 1024..2047), Vt [1024][4096] bf16
// (row = h*64+d, col = b*2048+s).  Out [4096][1024] f32.
// grid (16 q-tiles of 128, 32 bh), 512 threads = 8 waves, each wave owns 16
// q-rows, ALL waves share the k-range. Per 64-k tile, K (64x64) and V (64x64)
// are staged once into LDS via global_load_lds (1 K-chunk + 1 V-chunk per
// wave), XOR-swizzled via pre-swizzled GLOBAL source (rule: linear LDS dest +
// inverse-swz source + swz read). 2-phase pipeline: stage(t+1) issued before
// compute(t); counted vmcnt + raw s_barrier (no full drain).
__global__ __launch_bounds__(512, 4) void attn_fwd(
    const bf16* __restrict__ QK, const bf16* __restrict__ Vt,
    float* __restrict__ Out)
{
  const int LDK = 2048;
  const int qt = blockIdx.x;
  const int bh = blockIdx.y;
  const int b = bh >> 4, h = bh & 15;
  const int tid = threadIdx.x;
  const int wave = tid >> 6, lane = tid & 63;
  const int fr = lane & 15, fg = lane >> 4;
  const int f7 = fr & 7;

  const short* base = (const short*)QK + (size_t)b * 2048 * LDK;
  const short* Qp = base + h * 64;
  const short* Kp = base + 1024 + h * 64;
  const short* Vp = (const short*)Vt + (size_t)h * 64 * 4096 + b * 2048;
  const int q0 = qt * 128 + wave * 16;

  // LDS: K tile [64 k][64 d] and V tile [64 d][64 k], both row=128B,
  // 16B-chunk index XOR-swizzled by (row&7). Double buffered.
  __shared__ short Kbuf[2][64 * 64];
  __shared__ short Vbuf[2][64 * 64];
  __shared__ short P_lds[8][16 * 72];
  short* Pw = P_lds[wave];

  // staging source addresses (per lane): chunk s = wave, row = 8s + (l>>3),
  // logical 16B-chunk = (l&7) ^ (l>>3)   [inverse of the read-side swizzle]
  const int rsub = lane >> 3;              // 0..7
  const int clog = (lane & 7) ^ rsub;      // source chunk (shorts: *8)
  const short* Ksrc = Kp + (size_t)(8 * wave + rsub) * LDK + clog * 8;
  const short* Vsrc = Vp + (size_t)(8 * wave + rsub) * 4096 + clog * 8;

  // Q fragment, pre-scaled by 1/sqrt(64) = 0.125 (exact in bf16)
  s16x8 qf0 = *(const s16x8*)(Qp + (size_t)(q0 + fr) * LDK + fg * 8);
  s16x8 qf1 = *(const s16x8*)(Qp + (size_t)(q0 + fr) * LDK + 32 + fg * 8);
#pragma unroll
  for (int i = 0; i < 8; ++i) {
    qf0[i] = f2bf(bf2f(qf0[i]) * 0.125f);
    qf1[i] = f2bf(bf2f(qf1[i]) * 0.125f);
  }

  f32x4 acc[4] = {};
  f32x4 mrow = {-1e30f, -1e30f, -1e30f, -1e30f};
  f32x4 lrow = {};   // per-lane partial; fr-reduced once at the end

#define STAGE(bi, kt)                                                          \
  do {                                                                         \
    __builtin_amdgcn_global_load_lds(                                          \
        (const __attribute__((address_space(1))) uint32_t*)(Ksrc + (size_t)(kt) * LDK), \
        (__attribute__((address_space(3))) uint32_t*)(&Kbuf[bi][wave * 512]),  \
        16, 0, 0);                                                             \
    __builtin_amdgcn_global_load_lds(                                          \
        (const __attribute__((address_space(1))) uint32_t*)(Vsrc + (kt)),      \
        (__attribute__((address_space(3))) uint32_t*)(&Vbuf[bi][wave * 512]),  \
        16, 0, 0);                                                             \
  } while (0)

  int cur = 0;
  STAGE(0, 0);

  for (int kt = 0; kt < 2048; kt += 64) {
    // ---- phase A: prefetch next tile, then wait for current tile ----
    if (kt + 64 < 2048) {
      STAGE(cur ^ 1, kt + 64);
      asm volatile("s_waitcnt vmcnt(2)" ::: "memory");
    } else {
      asm volatile("s_waitcnt vmcnt(0)" ::: "memory");
    }
    __builtin_amdgcn_s_barrier();          // all waves' chunks landed
    __builtin_amdgcn_sched_barrier(0);

    const short* Kb = Kbuf[cur];
    const short* Vb = Vbuf[cur];

    // ---- QK^T: e[t] = 16x16 tile (q rows x k cols), swizzled LDS reads ----
    f32x4 e[4];
#pragma unroll
    for (int t = 0; t < 4; ++t) {
      const int ro = (t * 16 + fr) * 64;
      const s16x8 k0 = *(const s16x8*)(Kb + ro + ((fg ^ f7) << 3));
      const s16x8 k1 = *(const s16x8*)(Kb + ro + (((4 + fg) ^ f7) << 3));
      f32x4 z = {};
      z = __builtin_amdgcn_mfma_f32_16x16x32_bf16(qf0, k0, z, 0, 0, 0);
      z = __builtin_amdgcn_mfma_f32_16x16x32_bf16(qf1, k1, z, 0, 0, 0);
      e[t] = z;
    }

    // ---- per-lane defer-max: cross-lane tree + rescale only on growth > 8 ----
    f32x4 lmx;
#pragma unroll
    for (int j = 0; j < 4; ++j)
      lmx[j] = fmaxf(fmaxf(e[0][j], e[1][j]), fmaxf(e[2][j], e[3][j]));
    const bool need = (lmx[0] > mrow[0] + 8.f) | (lmx[1] > mrow[1] + 8.f) |
                      (lmx[2] > mrow[2] + 8.f) | (lmx[3] > mrow[3] + 8.f);
    if (__any(need)) {
      f32x4 mx = lmx;
#pragma unroll
      for (int d = 1; d < 16; d <<= 1)
#pragma unroll
        for (int j = 0; j < 4; ++j) mx[j] = fmaxf(mx[j], __shfl_xor(mx[j], d));
#pragma unroll
      for (int j = 0; j < 4; ++j) {
        const float mn = fmaxf(mrow[j], mx[j]);
        const float al = __expf(mrow[j] - mn);
        lrow[j] *= al;
        mrow[j] = mn;
#pragma unroll
        for (int nn = 0; nn < 4; ++nn) acc[nn][j] *= al;
      }
    }

    // ---- exp in place + per-lane partial row-sum ----
#pragma unroll
    for (int j = 0; j < 4; ++j) {
#pragma unroll
      for (int t = 0; t < 4; ++t) e[t][j] = __expf(e[t][j] - mrow[j]);
      lrow[j] += (e[0][j] + e[1][j]) + (e[2][j] + e[3][j]);
    }

    // ---- P transpose through wave-private LDS (in-order DS, no barrier) ----
#pragma unroll
    for (int t = 0; t < 4; ++t)
#pragma unroll
      for (int j = 0; j < 4; ++j)
        Pw[(fg * 4 + j) * 72 + t * 16 + fr] = f2bf(e[t][j]);
    const s16x8 pf0 = *(const s16x8*)(Pw + fr * 72 + fg * 8);
    const s16x8 pf1 = *(const s16x8*)(Pw + fr * 72 + 32 + fg * 8);

    // ---- PV from swizzled V tile ----
#pragma unroll
    for (int nn = 0; nn < 4; ++nn) {
      const int ro = (nn * 16 + fr) * 64;
      const s16x8 vf0 = *(const s16x8*)(Vb + ro + ((fg ^ f7) << 3));
      const s16x8 vf1 = *(const s16x8*)(Vb + ro + (((4 + fg) ^ f7) << 3));
      acc[nn] = __builtin_amdgcn_mfma_f32_16x16x32_bf16(pf0, vf0, acc[nn], 0, 0, 0);
      acc[nn] = __builtin_amdgcn_mfma_f32_16x16x32_bf16(pf1, vf1, acc[nn], 0, 0, 0);
    }

    // ---- end barrier: everyone done reading buf[cur]; next iter's STAGE
    //      may overwrite it only after this point ----
    __builtin_amdgcn_s_barrier();
    __builtin_amdgcn_sched_barrier(0);
    cur ^= 1;
  }
#undef STAGE

  // ---- final fr-reduction of lrow, normalize + store ----
#pragma unroll
  for (int d = 1; d < 16; d <<= 1)
#pragma unroll
    for (int j = 0; j < 4; ++j) lrow[j] += __shfl_xor(lrow[j], d);
  f32x4 inv;
#pragma unroll
  for (int j = 0; j < 4; ++j) inv[j] = 1.0f / lrow[j];
  float* outp = Out + (size_t)(b * 2048 + q0) * 1024 + h * 64;
#pragma unroll
  for (int nn = 0; nn < 4; ++nn)
#pragma unroll
    for (int j = 0; j < 4; ++j)
      outp[(size_t)(fg * 4 + j) * 1024 + nn * 16 + fr] = acc[nn][j] * inv[j];
}

// ---------------------------------------------------------------------------
extern "C" void kernel_launch(void* const* d_in, const int* in_sizes, int n_in,
                              void* d_out, int out_size, void* d_ws, size_t ws_size,
                              hipStream_t stream)
{
  const float* x   = (const float*)d_in[0];
  const float* Wq  = (const float*)d_in[1];
  const float* Wk  = (const float*)d_in[2];
  const float* Wv  = (const float*)d_in[3];
  const float* W1  = (const float*)d_in[4];
  const float* b1  = (const float*)d_in[5];
  const float* W2  = (const float*)d_in[6];
  const float* b2  = (const float*)d_in[7];
  const float* g1  = (const float*)d_in[8];
  const float* be1 = (const float*)d_in[9];
  const float* g2  = (const float*)d_in[10];
  const float* be2 = (const float*)d_in[11];
  float* out = (float*)d_out;

  const int M = 4096, D = 1024, DF = 4096;

  // workspace layout (lifetime-overlapped), total ~86 MB
  bf16* Wqk_t = (bf16*)d_ws;                        // [2048][1024]
  bf16* Wv_t  = Wqk_t + (size_t)2048 * 1024;        // [1024][1024]
  bf16* W1t   = Wv_t + (size_t)1024 * 1024;         // [4096][1024]
  bf16* W2t   = W1t + (size_t)4096 * 1024;          // [1024][4096]
  bf16* big   = W2t + (size_t)4096 * 1024;          // 16M elems = 32MB
  bf16* QK    = big;                                // [4096][2048] (dead after attn)
  bf16* Vt    = big + (size_t)8 * 1024 * 1024;      // [1024][4096] (dead after attn)
  bf16* hbuf  = big;                                // [4096][4096] (FFN1 out)
  char* p2    = (char*)(big + (size_t)16 * 1024 * 1024);
  bf16* xnorm = (bf16*)p2;                          // [4096][1024] (dead after gemms)
  float* attnO = (float*)p2;                        // [4096][1024] f32 (reuses xnorm)
  char* p3    = p2 + (size_t)M * D * sizeof(float);
  bf16* xres  = (bf16*)p3;                          // [4096][1024]
  bf16* xnorm2 = xres + (size_t)M * D;              // [4096][1024]

  // 1. weight transpose+convert
  transpose_cvt<<<dim3(32, 32), 256, 0, stream>>>(Wq, Wqk_t, D, D);
  transpose_cvt<<<dim3(32, 32), 256, 0, stream>>>(Wk, Wqk_t + (size_t)D * D, D, D);
  transpose_cvt<<<dim3(32, 32), 256, 0, stream>>>(Wv, Wv_t, D, D);
  transpose_cvt<<<dim3(128, 32), 256, 0, stream>>>(W1, W1t, D, DF);
  transpose_cvt<<<dim3(32, 128), 256, 0, stream>>>(W2, W2t, DF, D);
  // 2. LN1
  ln_bf16<<<M, 256, 0, stream>>>(x, g1, be1, xnorm);
  // 3. QK projection (fused Wq|Wk), row-major [4096][2048]
  gemm_bt<0><<<(M / 128) * (2048 / 128), 256, 0, stream>>>(
      xnorm, Wqk_t, QK, nullptr, nullptr, M, 2048, D);
  // 4. V projection directly transposed: Vt[d][s] = sum_k Wv_t[d][k]*xnorm[s][k]
  gemm_bt<0><<<(D / 128) * (M / 128), 256, 0, stream>>>(
      Wv_t, xnorm, Vt, nullptr, nullptr, D, M, D);
  // 5. attention (8 waves sharing LDS-staged K/V tiles, 2-phase pipeline)
  attn_fwd<<<dim3(16, 32), 512, 0, stream>>>(QK, Vt, attnO);
  // 6. residual + LN2
  add_ln_bf16<<<M, 256, 0, stream>>>(attnO, x, g2, be2, xres, xnorm2);
  // 7. FFN1 (bias + relu fused)
  gemm_bt<1><<<(M / 128) * (DF / 128), 256, 0, stream>>>(
      xres, W1t, hbuf, b1, nullptr, M, DF, D);
  // 8. FFN2 (bias + x_norm2 add fused) -> f32 out
  gemm_bt<2><<<(M / 128) * (D / 128), 256, 0, stream>>>(
      hbuf, W2t, out, b2, xnorm2, M, D, DF);
}

// Round 7
// 247.998 us; speedup vs baseline: 1.4116x; 1.1017x over previous
//
#include <hip/hip_runtime.h>
#include <hip/hip_bf16.h>
#include <stdint.h>

typedef __hip_bfloat16 bf16;
typedef __attribute__((ext_vector_type(4))) float f32x4;
typedef __attribute__((ext_vector_type(8))) short s16x8;
typedef __attribute__((ext_vector_type(4))) short s16x4;

#define DEV static __device__ __forceinline__

DEV short f2bf(float f) {
  bf16 h = __float2bfloat16(f);
  short s;
  __builtin_memcpy(&s, &h, 2);
  return s;
}
DEV float bf2f(short s) {
  bf16 h;
  __builtin_memcpy(&h, &s, 2);
  return __bfloat162float(h);
}

// ------------- transpose + f32->bf16 convert: W[K][N] -> Wt[N][K] ----------
__global__ __launch_bounds__(256) void transpose_cvt(
    const float* __restrict__ W, bf16* __restrict__ Wt, int K, int N)
{
  __shared__ float tile[32][33];
  const int n0 = blockIdx.x << 5;
  const int k0 = blockIdx.y << 5;
  const int tx = threadIdx.x & 31, ty = threadIdx.x >> 5;
#pragma unroll
  for (int i = 0; i < 4; ++i)
    tile[ty + i * 8][tx] = W[(size_t)(k0 + ty + i * 8) * N + n0 + tx];
  __syncthreads();
#pragma unroll
  for (int i = 0; i < 4; ++i)
    Wt[(size_t)(n0 + ty + i * 8) * K + k0 + tx] = __float2bfloat16(tile[tx][ty + i * 8]);
}

// ------------- layernorm (f32 in, bf16 out), D = 1024 ---------------------
__global__ __launch_bounds__(256) void ln_bf16(
    const float* __restrict__ x, const float* __restrict__ g,
    const float* __restrict__ be, bf16* __restrict__ out)
{
  const int t = threadIdx.x;
  const size_t row = blockIdx.x;
  const float4 v = ((const float4*)(x + row * 1024))[t];
  float s = v.x + v.y + v.z + v.w;
  float ss = v.x * v.x + v.y * v.y + v.z * v.z + v.w * v.w;
#pragma unroll
  for (int off = 32; off > 0; off >>= 1) {
    s += __shfl_down(s, off);
    ss += __shfl_down(ss, off);
  }
  __shared__ float sh[8];
  const int wave = t >> 6, lane = t & 63;
  if (!lane) { sh[wave] = s; sh[4 + wave] = ss; }
  __syncthreads();
  s = sh[0] + sh[1] + sh[2] + sh[3];
  ss = sh[4] + sh[5] + sh[6] + sh[7];
  const float mean = s * (1.f / 1024.f);
  const float rstd = rsqrtf(ss * (1.f / 1024.f) - mean * mean + 1e-5f);
  const float4 gv = ((const float4*)g)[t];
  const float4 bv = ((const float4*)be)[t];
  s16x4 o;
  o[0] = f2bf((v.x - mean) * rstd * gv.x + bv.x);
  o[1] = f2bf((v.y - mean) * rstd * gv.y + bv.y);
  o[2] = f2bf((v.z - mean) * rstd * gv.z + bv.z);
  o[3] = f2bf((v.w - mean) * rstd * gv.w + bv.w);
  ((s16x4*)(out + row * 1024))[t] = o;
}

// ------------- residual add + layernorm ------------------------------------
__global__ __launch_bounds__(256) void add_ln_bf16(
    const float* __restrict__ a, const float* __restrict__ x,
    const float* __restrict__ g, const float* __restrict__ be,
    bf16* __restrict__ xres, bf16* __restrict__ xnorm)
{
  const int t = threadIdx.x;
  const size_t row = blockIdx.x;
  const float4 av = ((const float4*)(a + row * 1024))[t];
  const float4 xv = ((const float4*)(x + row * 1024))[t];
  float4 v;
  v.x = av.x + xv.x; v.y = av.y + xv.y; v.z = av.z + xv.z; v.w = av.w + xv.w;
  float s = v.x + v.y + v.z + v.w;
  float ss = v.x * v.x + v.y * v.y + v.z * v.z + v.w * v.w;
#pragma unroll
  for (int off = 32; off > 0; off >>= 1) {
    s += __shfl_down(s, off);
    ss += __shfl_down(ss, off);
  }
  __shared__ float sh[8];
  const int wave = t >> 6, lane = t & 63;
  if (!lane) { sh[wave] = s; sh[4 + wave] = ss; }
  __syncthreads();
  s = sh[0] + sh[1] + sh[2] + sh[3];
  ss = sh[4] + sh[5] + sh[6] + sh[7];
  const float mean = s * (1.f / 1024.f);
  const float rstd = rsqrtf(ss * (1.f / 1024.f) - mean * mean + 1e-5f);
  const float4 gv = ((const float4*)g)[t];
  const float4 bv = ((const float4*)be)[t];
  s16x4 r, o;
  r[0] = f2bf(v.x); r[1] = f2bf(v.y); r[2] = f2bf(v.z); r[3] = f2bf(v.w);
  o[0] = f2bf((v.x - mean) * rstd * gv.x + bv.x);
  o[1] = f2bf((v.y - mean) * rstd * gv.y + bv.y);
  o[2] = f2bf((v.z - mean) * rstd * gv.z + bv.z);
  o[3] = f2bf((v.w - mean) * rstd * gv.w + bv.w);
  ((s16x4*)(xres + row * 1024))[t] = r;
  ((s16x4*)(xnorm + row * 1024))[t] = o;
}

// ------------- GEMM: C[M][N] = A[M][K] @ Bt[N][K]^T, bf16 MFMA -------------
// 128x128 tile, BK=64, DOUBLE-buffered LDS 2-phase: stage(next) issued before
// compute(cur); ONE __syncthreads per iter AFTER compute (drain overlapped).
// Static buffer names (2x unroll). XCD-bijective swizzle. T2 XOR swizzle
// (conflict-free, verified 0 conflicts in R6).
// EPI 0: C bf16 plain. EPI 1: bf16 relu(C + bias). EPI 2: f32 C + bias + add.
template <int EPI>
__global__ __launch_bounds__(256) void gemm_bt(
    const bf16* __restrict__ A, const bf16* __restrict__ Bt,
    void* __restrict__ C, const float* __restrict__ bias,
    const bf16* __restrict__ add_bf16, int M, int N, int K)
{
  __shared__ bf16 sA0[128 * 64];
  __shared__ bf16 sB0[128 * 64];
  __shared__ bf16 sA1[128 * 64];
  __shared__ bf16 sB1[128 * 64];
  const int tid = threadIdx.x;
  const int wave = tid >> 6, lane = tid & 63;
  const int fr = lane & 15, fg = lane >> 4;
  const int f7 = fr & 7;
  const int wr = wave >> 1, wc = wave & 1;
  const int nbx = N >> 7;
  // bijective XCD-aware swizzle (all our grids are %8==0; fall back otherwise)
  int bid = blockIdx.x;
  if ((gridDim.x & 7) == 0) {
    const int cpx = gridDim.x >> 3;
    bid = (bid & 7) * cpx + (bid >> 3);
  }
  const int brow = (bid / nbx) << 7;
  const int bcol = (bid % nbx) << 7;

  f32x4 acc[4][4] = {};

  // staging: each wave stages 32 rows (4 loads x 8 rows) of A and of B.
  // lane -> row_sub = lane>>3, phys chunk = lane&7, logical chunk = phys ^ row_sub
  const int rsub = lane >> 3;              // 0..7
  const int cl = (lane & 7) ^ rsub;        // logical 16B chunk in source row
  size_t ga[4], gb[4];
  int la[4];
#pragma unroll
  for (int j = 0; j < 4; ++j) {
    const int r = wave * 32 + j * 8;       // first row of this load
    ga[j] = (size_t)(brow + r + rsub) * K + cl * 8;
    gb[j] = (size_t)(bcol + r + rsub) * K + cl * 8;
    la[j] = r * 64;                        // wave-uniform LDS base (elements)
  }

#define GSTAGE(SA, SB, kt)                                                     \
  do {                                                                         \
    _Pragma("unroll")                                                          \
    for (int j = 0; j < 4; ++j) {                                              \
      __builtin_amdgcn_global_load_lds(                                        \
          (const __attribute__((address_space(1))) uint32_t*)(A + ga[j] + (kt)), \
          (__attribute__((address_space(3))) uint32_t*)(&SA[la[j]]), 16, 0, 0);  \
      __builtin_amdgcn_global_load_lds(                                        \
          (const __attribute__((address_space(1))) uint32_t*)(Bt + gb[j] + (kt)),\
          (__attribute__((address_space(3))) uint32_t*)(&SB[la[j]]), 16, 0, 0);  \
    }                                                                          \
  } while (0)

#define COMPUTE(SA, SB)                                                        \
  do {                                                                         \
    s16x8 af[4][2], bfr[4][2];                                                 \
    _Pragma("unroll")                                                          \
    for (int m = 0; m < 4; ++m)                                                \
      _Pragma("unroll")                                                        \
      for (int kk = 0; kk < 2; ++kk)                                           \
        af[m][kk] = *(const s16x8*)(&SA[(wr * 64 + m * 16 + fr) * 64 +         \
                                        (((kk * 4 + fg) ^ f7) << 3)]);         \
    _Pragma("unroll")                                                          \
    for (int n = 0; n < 4; ++n)                                                \
      _Pragma("unroll")                                                        \
      for (int kk = 0; kk < 2; ++kk)                                           \
        bfr[n][kk] = *(const s16x8*)(&SB[(wc * 64 + n * 16 + fr) * 64 +        \
                                         (((kk * 4 + fg) ^ f7) << 3)]);        \
    _Pragma("unroll")                                                          \
    for (int kk = 0; kk < 2; ++kk)                                             \
      _Pragma("unroll")                                                        \
      for (int m = 0; m < 4; ++m)                                              \
        _Pragma("unroll")                                                      \
        for (int n = 0; n < 4; ++n)                                            \
          acc[m][n] = __builtin_amdgcn_mfma_f32_16x16x32_bf16(                 \
              af[m][kk], bfr[n][kk], acc[m][n], 0, 0, 0);                      \
  } while (0)

  GSTAGE(sA0, sB0, 0);
  __syncthreads();

  // 2-phase pipeline, statically unrolled by 2 (K/64 is even for all shapes)
  int kt = 0;
  for (;;) {
    // phase 0: compute buf0, prefetch into buf1
    if (kt + 64 < K) {
      GSTAGE(sA1, sB1, kt + 64);
      COMPUTE(sA0, sB0);
      __syncthreads();   // drains staging (vmcnt0) + frees buf0 for overwrite
    } else {
      COMPUTE(sA0, sB0);
      break;
    }
    kt += 64;
    // phase 1: compute buf1, prefetch into buf0
    if (kt + 64 < K) {
      GSTAGE(sA0, sB0, kt + 64);
      COMPUTE(sA1, sB1);
      __syncthreads();
    } else {
      COMPUTE(sA1, sB1);
      break;
    }
    kt += 64;
  }
#undef GSTAGE
#undef COMPUTE

  const int crow = brow + wr * 64;
  const int ccol = bcol + wc * 64;
#pragma unroll
  for (int m = 0; m < 4; ++m) {
#pragma unroll
    for (int n = 0; n < 4; ++n) {
      const int col = ccol + n * 16 + fr;
#pragma unroll
      for (int j = 0; j < 4; ++j) {
        const int row = crow + m * 16 + fg * 4 + j;
        float v = acc[m][n][j];
        if (EPI == 0) {
          ((bf16*)C)[(size_t)row * N + col] = __float2bfloat16(v);
        } else if (EPI == 1) {
          v += bias[col];
          v = fmaxf(v, 0.f);
          ((bf16*)C)[(size_t)row * N + col] = __float2bfloat16(v);
        } else {
          float a;
          {
            bf16 hb = add_bf16[(size_t)row * N + col];
            a = __bfloat162float(hb);
          }
          ((float*)C)[(size_t)row * N + col] = v + bias[col] + a;
        }
      }
    }
  }
}

// ------------- flash attention v4 ------------------------------------------
// QK [4096][2048] bf16 (Q cols 0..1023, K cols 1024..2047), Vt [1024][4096] bf16
// (row = h*64+d, col = b*2048+s).  Out [4096][1024] f32.
// grid (16 q-tiles of 128, 32 bh), 512 threads = 8 waves, each wave owns 16
// q-rows, ALL waves share the k-range. Per 64-k tile, K (64x64) and V (64x64)
// are staged once into LDS via global_load_lds (1 K-chunk + 1 V-chunk per
// wave), XOR-swizzled via pre-swizzled GLOBAL source (rule: linear LDS dest +
// inverse-swz source + swz read). 2-phase pipeline: stage(t+1) issued before
// compute(t); counted vmcnt + raw s_barrier (no full drain).
__global__ __launch_bounds__(512, 4) void attn_fwd(
    const bf16* __restrict__ QK, const bf16* __restrict__ Vt,
    float* __restrict__ Out)
{
  const int LDK = 2048;
  const int qt = blockIdx.x;
  const int bh = blockIdx.y;
  const int b = bh >> 4, h = bh & 15;
  const int tid = threadIdx.x;
  const int wave = tid >> 6, lane = tid & 63;
  const int fr = lane & 15, fg = lane >> 4;
  const int f7 = fr & 7;

  const short* base = (const short*)QK + (size_t)b * 2048 * LDK;
  const short* Qp = base + h * 64;
  const short* Kp = base + 1024 + h * 64;
  const short* Vp = (const short*)Vt + (size_t)h * 64 * 4096 + b * 2048;
  const int q0 = qt * 128 + wave * 16;

  // LDS: K tile [64 k][64 d] and V tile [64 d][64 k], both row=128B,
  // 16B-chunk index XOR-swizzled by (row&7). Double buffered.
  __shared__ short Kbuf[2][64 * 64];
  __shared__ short Vbuf[2][64 * 64];
  __shared__ short P_lds[8][16 * 72];
  short* Pw = P_lds[wave];

  // staging source addresses (per lane): chunk s = wave, row = 8s + (l>>3),
  // logical 16B-chunk = (l&7) ^ (l>>3)   [inverse of the read-side swizzle]
  const int rsub = lane >> 3;              // 0..7
  const int clog = (lane & 7) ^ rsub;      // source chunk (shorts: *8)
  const short* Ksrc = Kp + (size_t)(8 * wave + rsub) * LDK + clog * 8;
  const short* Vsrc = Vp + (size_t)(8 * wave + rsub) * 4096 + clog * 8;

  // Q fragment, pre-scaled by 1/sqrt(64) = 0.125 (exact in bf16)
  s16x8 qf0 = *(const s16x8*)(Qp + (size_t)(q0 + fr) * LDK + fg * 8);
  s16x8 qf1 = *(const s16x8*)(Qp + (size_t)(q0 + fr) * LDK + 32 + fg * 8);
#pragma unroll
  for (int i = 0; i < 8; ++i) {
    qf0[i] = f2bf(bf2f(qf0[i]) * 0.125f);
    qf1[i] = f2bf(bf2f(qf1[i]) * 0.125f);
  }

  f32x4 acc[4] = {};
  f32x4 mrow = {-1e30f, -1e30f, -1e30f, -1e30f};
  f32x4 lrow = {};   // per-lane partial; fr-reduced once at the end

#define STAGE(bi, kt)                                                          \
  do {                                                                         \
    __builtin_amdgcn_global_load_lds(                                          \
        (const __attribute__((address_space(1))) uint32_t*)(Ksrc + (size_t)(kt) * LDK), \
        (__attribute__((address_space(3))) uint32_t*)(&Kbuf[bi][wave * 512]),  \
        16, 0, 0);                                                             \
    __builtin_amdgcn_global_load_lds(                                          \
        (const __attribute__((address_space(1))) uint32_t*)(Vsrc + (kt)),      \
        (__attribute__((address_space(3))) uint32_t*)(&Vbuf[bi][wave * 512]),  \
        16, 0, 0);                                                             \
  } while (0)

  int cur = 0;
  STAGE(0, 0);

  for (int kt = 0; kt < 2048; kt += 64) {
    // ---- phase A: prefetch next tile, then wait for current tile ----
    if (kt + 64 < 2048) {
      STAGE(cur ^ 1, kt + 64);
      asm volatile("s_waitcnt vmcnt(2)" ::: "memory");
    } else {
      asm volatile("s_waitcnt vmcnt(0)" ::: "memory");
    }
    __builtin_amdgcn_s_barrier();          // all waves' chunks landed
    __builtin_amdgcn_sched_barrier(0);

    const short* Kb = Kbuf[cur];
    const short* Vb = Vbuf[cur];

    // ---- QK^T: e[t] = 16x16 tile (q rows x k cols), swizzled LDS reads ----
    f32x4 e[4];
#pragma unroll
    for (int t = 0; t < 4; ++t) {
      const int ro = (t * 16 + fr) * 64;
      const s16x8 k0 = *(const s16x8*)(Kb + ro + ((fg ^ f7) << 3));
      const s16x8 k1 = *(const s16x8*)(Kb + ro + (((4 + fg) ^ f7) << 3));
      f32x4 z = {};
      z = __builtin_amdgcn_mfma_f32_16x16x32_bf16(qf0, k0, z, 0, 0, 0);
      z = __builtin_amdgcn_mfma_f32_16x16x32_bf16(qf1, k1, z, 0, 0, 0);
      e[t] = z;
    }

    // ---- per-lane defer-max: cross-lane tree + rescale only on growth > 8 ----
    f32x4 lmx;
#pragma unroll
    for (int j = 0; j < 4; ++j)
      lmx[j] = fmaxf(fmaxf(e[0][j], e[1][j]), fmaxf(e[2][j], e[3][j]));
    const bool need = (lmx[0] > mrow[0] + 8.f) | (lmx[1] > mrow[1] + 8.f) |
                      (lmx[2] > mrow[2] + 8.f) | (lmx[3] > mrow[3] + 8.f);
    if (__any(need)) {
      f32x4 mx = lmx;
#pragma unroll
      for (int d = 1; d < 16; d <<= 1)
#pragma unroll
        for (int j = 0; j < 4; ++j) mx[j] = fmaxf(mx[j], __shfl_xor(mx[j], d));
#pragma unroll
      for (int j = 0; j < 4; ++j) {
        const float mn = fmaxf(mrow[j], mx[j]);
        const float al = __expf(mrow[j] - mn);
        lrow[j] *= al;
        mrow[j] = mn;
#pragma unroll
        for (int nn = 0; nn < 4; ++nn) acc[nn][j] *= al;
      }
    }

    // ---- exp in place + per-lane partial row-sum ----
#pragma unroll
    for (int j = 0; j < 4; ++j) {
#pragma unroll
      for (int t = 0; t < 4; ++t) e[t][j] = __expf(e[t][j] - mrow[j]);
      lrow[j] += (e[0][j] + e[1][j]) + (e[2][j] + e[3][j]);
    }

    // ---- P transpose through wave-private LDS (in-order DS, no barrier) ----
#pragma unroll
    for (int t = 0; t < 4; ++t)
#pragma unroll
      for (int j = 0; j < 4; ++j)
        Pw[(fg * 4 + j) * 72 + t * 16 + fr] = f2bf(e[t][j]);
    const s16x8 pf0 = *(const s16x8*)(Pw + fr * 72 + fg * 8);
    const s16x8 pf1 = *(const s16x8*)(Pw + fr * 72 + 32 + fg * 8);

    // ---- PV from swizzled V tile ----
#pragma unroll
    for (int nn = 0; nn < 4; ++nn) {
      const int ro = (nn * 16 + fr) * 64;
      const s16x8 vf0 = *(const s16x8*)(Vb + ro + ((fg ^ f7) << 3));
      const s16x8 vf1 = *(const s16x8*)(Vb + ro + (((4 + fg) ^ f7) << 3));
      acc[nn] = __builtin_amdgcn_mfma_f32_16x16x32_bf16(pf0, vf0, acc[nn], 0, 0, 0);
      acc[nn] = __builtin_amdgcn_mfma_f32_16x16x32_bf16(pf1, vf1, acc[nn], 0, 0, 0);
    }

    // ---- end barrier: everyone done reading buf[cur]; next iter's STAGE
    //      may overwrite it only after this point ----
    __builtin_amdgcn_s_barrier();
    __builtin_amdgcn_sched_barrier(0);
    cur ^= 1;
  }
#undef STAGE

  // ---- final fr-reduction of lrow, normalize + store ----
#pragma unroll
  for (int d = 1; d < 16; d <<= 1)
#pragma unroll
    for (int j = 0; j < 4; ++j) lrow[j] += __shfl_xor(lrow[j], d);
  f32x4 inv;
#pragma unroll
  for (int j = 0; j < 4; ++j) inv[j] = 1.0f / lrow[j];
  float* outp = Out + (size_t)(b * 2048 + q0) * 1024 + h * 64;
#pragma unroll
  for (int nn = 0; nn < 4; ++nn)
#pragma unroll
    for (int j = 0; j < 4; ++j)
      outp[(size_t)(fg * 4 + j) * 1024 + nn * 16 + fr] = acc[nn][j] * inv[j];
}

// ---------------------------------------------------------------------------
extern "C" void kernel_launch(void* const* d_in, const int* in_sizes, int n_in,
                              void* d_out, int out_size, void* d_ws, size_t ws_size,
                              hipStream_t stream)
{
  const float* x   = (const float*)d_in[0];
  const float* Wq  = (const float*)d_in[1];
  const float* Wk  = (const float*)d_in[2];
  const float* Wv  = (const float*)d_in[3];
  const float* W1  = (const float*)d_in[4];
  const float* b1  = (const float*)d_in[5];
  const float* W2  = (const float*)d_in[6];
  const float* b2  = (const float*)d_in[7];
  const float* g1  = (const float*)d_in[8];
  const float* be1 = (const float*)d_in[9];
  const float* g2  = (const float*)d_in[10];
  const float* be2 = (const float*)d_in[11];
  float* out = (float*)d_out;

  const int M = 4096, D = 1024, DF = 4096;

  // workspace layout (lifetime-overlapped), total ~86 MB
  bf16* Wqk_t = (bf16*)d_ws;                        // [2048][1024]
  bf16* Wv_t  = Wqk_t + (size_t)2048 * 1024;        // [1024][1024]
  bf16* W1t   = Wv_t + (size_t)1024 * 1024;         // [4096][1024]
  bf16* W2t   = W1t + (size_t)4096 * 1024;          // [1024][4096]
  bf16* big   = W2t + (size_t)4096 * 1024;          // 16M elems = 32MB
  bf16* QK    = big;                                // [4096][2048] (dead after attn)
  bf16* Vt    = big + (size_t)8 * 1024 * 1024;      // [1024][4096] (dead after attn)
  bf16* hbuf  = big;                                // [4096][4096] (FFN1 out)
  char* p2    = (char*)(big + (size_t)16 * 1024 * 1024);
  bf16* xnorm = (bf16*)p2;                          // [4096][1024] (dead after gemms)
  float* attnO = (float*)p2;                        // [4096][1024] f32 (reuses xnorm)
  char* p3    = p2 + (size_t)M * D * sizeof(float);
  bf16* xres  = (bf16*)p3;                          // [4096][1024]
  bf16* xnorm2 = xres + (size_t)M * D;              // [4096][1024]

  // 1. weight transpose+convert
  transpose_cvt<<<dim3(32, 32), 256, 0, stream>>>(Wq, Wqk_t, D, D);
  transpose_cvt<<<dim3(32, 32), 256, 0, stream>>>(Wk, Wqk_t + (size_t)D * D, D, D);
  transpose_cvt<<<dim3(32, 32), 256, 0, stream>>>(Wv, Wv_t, D, D);
  transpose_cvt<<<dim3(128, 32), 256, 0, stream>>>(W1, W1t, D, DF);
  transpose_cvt<<<dim3(32, 128), 256, 0, stream>>>(W2, W2t, DF, D);
  // 2. LN1
  ln_bf16<<<M, 256, 0, stream>>>(x, g1, be1, xnorm);
  // 3. QK projection (fused Wq|Wk), row-major [4096][2048]
  gemm_bt<0><<<(M / 128) * (2048 / 128), 256, 0, stream>>>(
      xnorm, Wqk_t, QK, nullptr, nullptr, M, 2048, D);
  // 4. V projection directly transposed: Vt[d][s] = sum_k Wv_t[d][k]*xnorm[s][k]
  gemm_bt<0><<<(D / 128) * (M / 128), 256, 0, stream>>>(
      Wv_t, xnorm, Vt, nullptr, nullptr, D, M, D);
  // 5. attention (8 waves sharing LDS-staged K/V tiles, 2-phase pipeline)
  attn_fwd<<<dim3(16, 32), 512, 0, stream>>>(QK, Vt, attnO);
  // 6. residual + LN2
  add_ln_bf16<<<M, 256, 0, stream>>>(attnO, x, g2, be2, xres, xnorm2);
  // 7. FFN1 (bias + relu fused)
  gemm_bt<1><<<(M / 128) * (DF / 128), 256, 0, stream>>>(
      xres, W1t, hbuf, b1, nullptr, M, DF, D);
  // 8. FFN2 (bias + x_norm2 add fused) -> f32 out
  gemm_bt<2><<<(M / 128) * (D / 128), 256, 0, stream>>>(
      hbuf, W2t, out, b2, xnorm2, M, D, DF);
}